// Round 1
// baseline (523.602 us; speedup 1.0000x reference)
//
#include <hip/hip_runtime.h>
#include <hip/hip_fp16.h>
#include <hip/hip_cooperative_groups.h>

namespace cg = cooperative_groups;

// Capsule dynamic routing, fully fused into ONE cooperative kernel.
// x:[B,I,K]=32x2048x8, W:[J,I,D,K]=32x2048x16x8, out v:[B,J,D]=32x32x16.
// R6: the 7-dispatch pipeline was dispatch/round-trip bound, not roofline
// bound (pass FETCH=18.3MB showed Wt refetched from HBM each pass). Now:
// each block owns an 8-i chunk; W chunk converted fp32->f16 straight into
// LDS once (W read from HBM exactly once, no Wt buffer, no prep kernel);
// 3 routing iterations in-kernel with grid.sync() between pass and reduce.
// vsum accumulates in wave-0 registers; partials stay fp16 in ws.

#define ICAP    2048
#define JD      512          // JCAP*DDIM
#define S_ELEMS 16384        // BATCH*JCAP*DDIM
#define EPSQ    1e-7f
#define NBP     256          // blocks (one 8-i chunk each)
#define ICH     8            // i's per block
#define WROW    1040         // 64 slots x 16B + 16B pad (bank rotation on stage)
#define WIL     (8 * WROW)   // per-il LDS bytes (8 d_local rows)

typedef _Float16 h2v __attribute__((ext_vector_type(2)));
union H8 { int4 i4; h2v h[4]; };

#if defined(__has_builtin) && __has_builtin(__builtin_amdgcn_fdot2)
#define FDOT2(a, b, c) __builtin_amdgcn_fdot2((a), (b), (c), false)
#else
__device__ inline float FDOT2(h2v a, h2v b, float c) {
    return c + (float)a[0] * (float)b[0] + (float)a[1] * (float)b[1];
}
#endif
#if defined(__has_builtin) && __has_builtin(__builtin_amdgcn_rcpf)
#define FAST_RCP(x) __builtin_amdgcn_rcpf(x)
#else
#define FAST_RCP(x) (1.0f / (x))
#endif
#if defined(__has_builtin) && __has_builtin(__builtin_amdgcn_rsqf)
#define FAST_RSQ(x) __builtin_amdgcn_rsqf(x)
#else
#define FAST_RSQ(x) rsqrtf(x)
#endif

// ---------------------------------------------------------------------------
// Fused kernel: 256 blocks x 512 threads (8 waves), cooperative.
// Wave w owns b in {w, w+8, w+16, w+24}; lane l -> j = l&31, dh = l>>5.
// LDS: sWt 66.5KB (f16 W chunk, pass layout, 16B pad/row), sX 4KB, rbuf 2KB.
// ---------------------------------------------------------------------------
__global__ __launch_bounds__(512, 1)
void caps_fused(const float4* __restrict__ Wv, const float4* __restrict__ Xv,
                float* __restrict__ vsum, __half* __restrict__ partials,
                float* __restrict__ out)
{
    __shared__ __align__(16) unsigned char sWt[WIL * ICH];   // 66560 B
    __shared__ __align__(16) unsigned char sX[4096];         // 32b x 8il x 16B
    __shared__ float rbuf[8][64];

    const int tid = threadIdx.x;
    const int bid = blockIdx.x;
    const int i0  = bid * ICH;

    // ---- stage W: fp32 global -> f16 LDS in pass layout ----
    // slot (il, d&7 row, s=2j+dh) holds W[j, i0+il, d, k=0..7] as 8 halves.
#pragma unroll
    for (int it = 0; it < 16; ++it) {
        const int f  = it * 512 + tid;          // [0, 8192) float4s
        const int q4 = f & 31;                  // float4 within (j,il) row
        const int il = (f >> 5) & 7;
        const int jj = f >> 8;
        const float4 w = Wv[((size_t)jj * ICAP + (i0 + il)) * 32 + q4];
        ushort4 h;
        h.x = __half_as_ushort(__float2half(w.x));
        h.y = __half_as_ushort(__float2half(w.y));
        h.z = __half_as_ushort(__float2half(w.z));
        h.w = __half_as_ushort(__float2half(w.w));
        const int d   = q4 >> 1;
        const int sub = q4 & 1;
        *reinterpret_cast<ushort4*>(sWt + il * WIL + (d & 7) * WROW
                                    + (2 * jj + (d >> 3)) * 16 + sub * 8) = h;
    }
    // ---- stage x: fp32 global -> f16 LDS, slot (b*8+il)*16B = x[b,i,0..7] ----
    {
        const int k4 = tid & 1, il = (tid >> 1) & 7, b = tid >> 4;
        const float4 w = Xv[((size_t)b * ICAP + (i0 + il)) * 2 + k4];
        ushort4 h;
        h.x = __half_as_ushort(__float2half(w.x));
        h.y = __half_as_ushort(__float2half(w.y));
        h.z = __half_as_ushort(__float2half(w.z));
        h.w = __half_as_ushort(__float2half(w.w));
        *reinterpret_cast<ushort4*>(sX + (b * 8 + il) * 16 + k4 * 8) = h;
    }
    __syncthreads();

    const int wave = tid >> 6, lane = tid & 63;
    const int j = lane & 31, dh = lane >> 5;
    float vacc = 0.f;                            // wave-0: running vsum[e]

    cg::grid_group grid = cg::this_grid();

#pragma unroll
    for (int r = 0; r < 3; ++r) {
        const bool first = (r == 0);             // constant after unroll
        float vs[4][8], sacc[4][8];
#pragma unroll
        for (int bb = 0; bb < 4; ++bb) {
            const int b = wave + 8 * bb;
            if (!first) {
                const float* vp = vsum + b * JD + j * 16 + dh * 8;
                const float4 a  = *reinterpret_cast<const float4*>(vp);
                const float4 bq = *reinterpret_cast<const float4*>(vp + 4);
                vs[bb][0]=a.x; vs[bb][1]=a.y; vs[bb][2]=a.z; vs[bb][3]=a.w;
                vs[bb][4]=bq.x; vs[bb][5]=bq.y; vs[bb][6]=bq.z; vs[bb][7]=bq.w;
            }
#pragma unroll
            for (int q = 0; q < 8; ++q) sacc[bb][q] = 0.f;
        }

#pragma unroll
        for (int il = 0; il < ICH; ++il) {
            H8 w8[8];
#pragma unroll
            for (int cc = 0; cc < 8; ++cc)
                w8[cc].i4 = *reinterpret_cast<const int4*>(
                    sWt + il * WIL + cc * WROW + (2 * j + dh) * 16);
#pragma unroll
            for (int bb = 0; bb < 4; ++bb) {
                const int b = wave + 8 * bb;
                H8 xv;
                xv.i4 = *reinterpret_cast<const int4*>(sX + (b * 8 + il) * 16);

                float u[8], tpart = 0.f;
#pragma unroll
                for (int q = 0; q < 8; ++q) {
                    float acc = FDOT2(w8[q].h[0], xv.h[0], 0.f);
                    acc = FDOT2(w8[q].h[1], xv.h[1], acc);
                    acc = FDOT2(w8[q].h[2], xv.h[2], acc);
                    acc = FDOT2(w8[q].h[3], xv.h[3], acc);
                    u[q] = acc;
                    if (!first) tpart = fmaf(acc, vs[bb][q], tpart);
                }
                float c;
                if (first) {
                    c = 0.03125f;                // softmax(0) over 32 j's
                } else {
                    const float t = tpart + __shfl_xor(tpart, 32);
                    const float e = __expf(t);
                    float se = e;
#pragma unroll
                    for (int off = 1; off <= 16; off <<= 1)
                        se += __shfl_xor(se, off);
                    c = e * FAST_RCP(se);
                }
#pragma unroll
                for (int q = 0; q < 8; ++q)
                    sacc[bb][q] = fmaf(c, u[q], sacc[bb][q]);
            }
        }

        // fp16 partial slice, disjoint per block
        __half* pout = partials + (size_t)bid * S_ELEMS;
#pragma unroll
        for (int bb = 0; bb < 4; ++bb) {
            const int b = wave + 8 * bb;
            union { int4 v; __half2 h[4]; } pk;
#pragma unroll
            for (int q = 0; q < 4; ++q)
                pk.h[q] = __floats2half2_rn(sacc[bb][2 * q], sacc[bb][2 * q + 1]);
            *reinterpret_cast<int4*>(pout + b * JD + j * 16 + dh * 8) = pk.v;
        }

        __threadfence();
        grid.sync();

        // ---- reduce: block owns e in [bid*64, bid*64+64) ----
        {
            const int e = bid * 64 + lane;
            float s = 0.f;
            const __half* p = partials + (size_t)wave * 32 * S_ELEMS + e;
#pragma unroll
            for (int n = 0; n < 32; ++n)
                s += __half2float(p[(size_t)n * S_ELEMS]);
            rbuf[wave][lane] = s;
            __syncthreads();
            if (wave == 0) {
                s = 0.f;
#pragma unroll
                for (int k = 0; k < 8; ++k) s += rbuf[k][lane];
                float n2 = s * s;
#pragma unroll
                for (int off = 1; off <= 8; off <<= 1)
                    n2 += __shfl_xor(n2, off);
                const float scale = n2 * FAST_RCP(1.f + n2) * FAST_RSQ(n2 + EPSQ);
                const float v = s * scale;
                if (r == 2) {
                    out[e] = v;
                } else {
                    vacc += v;                   // vsum = sum of v's so far
                    vsum[e] = vacc;
                }
            }
        }
        if (r < 2) { __threadfence(); grid.sync(); }
    }
}

// ===========================================================================
// Fallback path (proven 7-kernel pipeline) — used only if cooperative launch
// is rejected by the runtime/graph capture.
// ===========================================================================
__global__ __launch_bounds__(256)
void caps_prep(const float4* __restrict__ Wv, const float* __restrict__ x,
               ushort4* __restrict__ Wt, __half* __restrict__ xh) {
    const int i = blockIdx.x;
    const int t = threadIdx.x;
#pragma unroll
    for (int q = 0; q < 4; ++q) {
        const int f  = q * 256 + t;
        const int jj = f >> 5, c = f & 31;
        const float4 w = Wv[(size_t)jj * 65536 + (size_t)i * 32 + c];
        ushort4 h;
        h.x = __half_as_ushort(__float2half(w.x));
        h.y = __half_as_ushort(__float2half(w.y));
        h.z = __half_as_ushort(__float2half(w.z));
        h.w = __half_as_ushort(__float2half(w.w));
        const int dh = c >> 4, cc = (c & 15) >> 1, sub = c & 1;
        Wt[((size_t)i * 512 + cc * 64 + 2 * jj + dh) * 2 + sub] = h;
    }
    const int b = t >> 3, k = t & 7;
    const size_t xi = ((size_t)b * ICAP + i) * 8 + k;
    xh[xi] = __float2half(x[xi]);
}

template <int FIRST>
__global__ __launch_bounds__(512, 1)
void caps_pass(const int4* __restrict__ Wt, const int4* __restrict__ xh,
               const float* __restrict__ vsum, __half* __restrict__ partials) {
    const int tid  = threadIdx.x;
    const int wave = tid >> 6;
    const int lane = tid & 63;
    const int j    = lane & 31;
    const int dh   = lane >> 5;
    const int i0   = blockIdx.x * ICH;

    float vs[4][8], sacc[4][8];
#pragma unroll
    for (int bb = 0; bb < 4; ++bb) {
        const int b = wave + 8 * bb;
        if (!FIRST) {
            const float* vp = vsum + b * JD + j * 16 + dh * 8;
            const float4 a  = *reinterpret_cast<const float4*>(vp);
            const float4 bq = *reinterpret_cast<const float4*>(vp + 4);
            vs[bb][0]=a.x; vs[bb][1]=a.y; vs[bb][2]=a.z; vs[bb][3]=a.w;
            vs[bb][4]=bq.x; vs[bb][5]=bq.y; vs[bb][6]=bq.z; vs[bb][7]=bq.w;
        }
#pragma unroll
        for (int q = 0; q < 8; ++q) sacc[bb][q] = 0.f;
    }

    const int4* wp = Wt + (size_t)i0 * 512 + 2 * j + dh;

#pragma unroll
    for (int il = 0; il < ICH; ++il) {
        H8 w8[8];
#pragma unroll
        for (int cc = 0; cc < 8; ++cc)
            w8[cc].i4 = wp[(size_t)il * 512 + cc * 64];

        const int gi = i0 + il;
#pragma unroll
        for (int bb = 0; bb < 4; ++bb) {
            const int b = wave + 8 * bb;
            H8 xv;
            xv.i4 = xh[(size_t)b * ICAP + gi];

            float u[8], tpart = 0.f;
#pragma unroll
            for (int q = 0; q < 8; ++q) {
                float acc = FDOT2(w8[q].h[0], xv.h[0], 0.f);
                acc = FDOT2(w8[q].h[1], xv.h[1], acc);
                acc = FDOT2(w8[q].h[2], xv.h[2], acc);
                acc = FDOT2(w8[q].h[3], xv.h[3], acc);
                u[q] = acc;
                if (!FIRST) tpart = fmaf(acc, vs[bb][q], tpart);
            }
            float c;
            if (FIRST) {
                c = 0.03125f;
            } else {
                const float t = tpart + __shfl_xor(tpart, 32);
                const float e = __expf(t);
                float se = e;
#pragma unroll
                for (int off = 1; off <= 16; off <<= 1)
                    se += __shfl_xor(se, off);
                c = e * FAST_RCP(se);
            }
#pragma unroll
            for (int q = 0; q < 8; ++q)
                sacc[bb][q] = fmaf(c, u[q], sacc[bb][q]);
        }
    }

    __half* pout = partials + (size_t)blockIdx.x * S_ELEMS;
#pragma unroll
    for (int bb = 0; bb < 4; ++bb) {
        const int b = wave + 8 * bb;
        union { int4 v; __half2 h[4]; } pk;
#pragma unroll
        for (int q = 0; q < 4; ++q)
            pk.h[q] = __floats2half2_rn(sacc[bb][2 * q], sacc[bb][2 * q + 1]);
        *reinterpret_cast<int4*>(pout + b * JD + j * 16 + dh * 8) = pk.v;
    }
}

__global__ __launch_bounds__(1024)
void caps_reduce(const __half* __restrict__ partials, float* __restrict__ vsum,
                 float* __restrict__ out, int first) {
    __shared__ float buf[16][80];
    const int tid = threadIdx.x;
    const int eL  = tid & 63;
    const int sg  = tid >> 6;
    const int e   = blockIdx.x * 64 + eL;

    float s = 0.f;
    const __half* p = partials + (size_t)sg * S_ELEMS + e;
#pragma unroll
    for (int n = 0; n < 16; ++n)
        s += __half2float(p[(size_t)(n * 16) * S_ELEMS]);
    buf[sg][eL] = s;
    __syncthreads();

    if (sg == 0) {
        s = 0.f;
#pragma unroll
        for (int k = 0; k < 16; ++k) s += buf[k][eL];
        float n2 = s * s;
#pragma unroll
        for (int off = 1; off <= 8; off <<= 1)
            n2 += __shfl_xor(n2, off);
        const float scale = n2 * FAST_RCP(1.f + n2) * FAST_RSQ(n2 + EPSQ);
        const float v = s * scale;
        const float old = first ? 0.f : vsum[e];
        vsum[e] = old + v;
        if (out) out[e] = v;
    }
}

extern "C" void kernel_launch(void* const* d_in, const int* in_sizes, int n_in,
                              void* d_out, int out_size, void* d_ws, size_t ws_size,
                              hipStream_t stream) {
    const float* x = (const float*)d_in[0];   // [32,2048,8]
    const float* W = (const float*)d_in[1];   // [32,2048,16,8]
    float* out = (float*)d_out;               // [32,32,16]

    // ws: vsum 64KB | partials fp16 8.39MB | (fallback only: Wt 16.78MB | xh 1MB)
    float*   vsum     = (float*)d_ws;
    __half*  partials = (__half*)((char*)d_ws + 65536);
    ushort4* Wt       = (ushort4*)((char*)partials + (size_t)NBP * S_ELEMS * 2);
    __half*  xh       = (__half*)((char*)Wt + (size_t)ICAP * 512 * 16);

    const float4* W4 = (const float4*)W;
    const float4* x4 = (const float4*)x;
    void* args[] = {(void*)&W4, (void*)&x4, (void*)&vsum, (void*)&partials,
                    (void*)&out};

    hipError_t cerr = hipLaunchCooperativeKernel(
        reinterpret_cast<const void*>(&caps_fused),
        dim3(NBP), dim3(512), args, 0, stream);

    if (cerr != hipSuccess) {
        (void)hipGetLastError();  // clear sticky error, use proven path
        caps_prep<<<ICAP, 256, 0, stream>>>((const float4*)W, x, Wt, xh);
        caps_pass<1><<<NBP, 512, 0, stream>>>((const int4*)Wt, (const int4*)xh,
                                              vsum, partials);
        caps_reduce<<<S_ELEMS / 64, 1024, 0, stream>>>(partials, vsum, nullptr, 1);
        caps_pass<0><<<NBP, 512, 0, stream>>>((const int4*)Wt, (const int4*)xh,
                                              vsum, partials);
        caps_reduce<<<S_ELEMS / 64, 1024, 0, stream>>>(partials, vsum, nullptr, 0);
        caps_pass<0><<<NBP, 512, 0, stream>>>((const int4*)Wt, (const int4*)xh,
                                              vsum, partials);
        caps_reduce<<<S_ELEMS / 64, 1024, 0, stream>>>(partials, vsum, out, 0);
    }
}

// Round 2
// 228.806 us; speedup vs baseline: 2.2884x; 2.2884x over previous
//
#include <hip/hip_runtime.h>
#include <hip/hip_fp16.h>

// Capsule dynamic routing, fully fused into ONE cooperative kernel.
// x:[B,I,K]=32x2048x8, W:[J,I,D,K]=32x2048x16x8, out v:[B,J,D]=32x32x16.
// R7: R6's cg::grid_group::sync() was the regression (VALUBusy 4%, HBM 1.5%
// -> 95% idle; ~85us per sync from ROCm's s_sleep slow path). Replaced with
// a hand-rolled device barrier: monotonic atomic counter + release flag on
// a separate cache line, thread-0-per-block spin with s_sleep(1), fanned out
// via __syncthreads. State zeroed by an 8..256B hipMemsetAsync node.
// Everything else (LDS-resident W f16 chunk, in-kernel 3-pass routing,
// fp16 partials, register vsum accumulation) is unchanged from R6.

#define ICAP    2048
#define JD      512          // JCAP*DDIM
#define S_ELEMS 16384        // BATCH*JCAP*DDIM
#define EPSQ    1e-7f
#define NBP     256          // blocks (one 8-i chunk each)
#define ICH     8            // i's per block
#define WROW    1040         // 64 slots x 16B + 16B pad (bank rotation on stage)
#define WIL     (8 * WROW)   // per-il LDS bytes (8 d_local rows)

typedef _Float16 h2v __attribute__((ext_vector_type(2)));
union H8 { int4 i4; h2v h[4]; };

#if defined(__has_builtin) && __has_builtin(__builtin_amdgcn_fdot2)
#define FDOT2(a, b, c) __builtin_amdgcn_fdot2((a), (b), (c), false)
#else
__device__ inline float FDOT2(h2v a, h2v b, float c) {
    return c + (float)a[0] * (float)b[0] + (float)a[1] * (float)b[1];
}
#endif
#if defined(__has_builtin) && __has_builtin(__builtin_amdgcn_rcpf)
#define FAST_RCP(x) __builtin_amdgcn_rcpf(x)
#else
#define FAST_RCP(x) (1.0f / (x))
#endif
#if defined(__has_builtin) && __has_builtin(__builtin_amdgcn_rsqf)
#define FAST_RSQ(x) __builtin_amdgcn_rsqf(x)
#else
#define FAST_RSQ(x) rsqrtf(x)
#endif

// ---------------------------------------------------------------------------
// Grid barrier: gb[0] = monotonic arrival counter, gb[32] (byte 128) =
// release generation. Barrier `gen` (1-based) completes when counter hits
// gen*NBP; last arriver publishes gen. Requires co-resident grid
// (cooperative launch) and zeroed state (memset node).
// ---------------------------------------------------------------------------
__device__ __forceinline__ void gsync(unsigned* gb, unsigned gen) {
    __syncthreads();
    if (threadIdx.x == 0) {
        __threadfence();   // prior global writes visible before arrival
        const unsigned prev = __hip_atomic_fetch_add(
            gb, 1u, __ATOMIC_ACQ_REL, __HIP_MEMORY_SCOPE_AGENT);
        if (prev == gen * NBP - 1u) {
            __hip_atomic_store(gb + 32, gen, __ATOMIC_RELEASE,
                               __HIP_MEMORY_SCOPE_AGENT);
        } else {
            unsigned r;
            do {
                __builtin_amdgcn_s_sleep(1);
                r = __hip_atomic_load(gb + 32, __ATOMIC_ACQUIRE,
                                      __HIP_MEMORY_SCOPE_AGENT);
            } while (r < gen);
        }
    }
    __syncthreads();
}

// ---------------------------------------------------------------------------
// Fused kernel: 256 blocks x 512 threads (8 waves), cooperative.
// Wave w owns b in {w, w+8, w+16, w+24}; lane l -> j = l&31, dh = l>>5.
// LDS: sWt 66.5KB (f16 W chunk, pass layout, 16B pad/row), sX 4KB, rbuf 2KB.
// ---------------------------------------------------------------------------
__global__ __launch_bounds__(512, 1)
void caps_fused(const float4* __restrict__ Wv, const float4* __restrict__ Xv,
                float* __restrict__ vsum, __half* __restrict__ partials,
                float* __restrict__ out, unsigned* __restrict__ gbar)
{
    __shared__ __align__(16) unsigned char sWt[WIL * ICH];   // 66560 B
    __shared__ __align__(16) unsigned char sX[4096];         // 32b x 8il x 16B
    __shared__ float rbuf[8][64];

    const int tid = threadIdx.x;
    const int bid = blockIdx.x;
    const int i0  = bid * ICH;

    // ---- stage W: fp32 global -> f16 LDS in pass layout ----
    // slot (il, d&7 row, s=2j+dh) holds W[j, i0+il, d, k=0..7] as 8 halves.
#pragma unroll
    for (int it = 0; it < 16; ++it) {
        const int f  = it * 512 + tid;          // [0, 8192) float4s
        const int q4 = f & 31;                  // float4 within (j,il) row
        const int il = (f >> 5) & 7;
        const int jj = f >> 8;
        const float4 w = Wv[((size_t)jj * ICAP + (i0 + il)) * 32 + q4];
        ushort4 h;
        h.x = __half_as_ushort(__float2half(w.x));
        h.y = __half_as_ushort(__float2half(w.y));
        h.z = __half_as_ushort(__float2half(w.z));
        h.w = __half_as_ushort(__float2half(w.w));
        const int d   = q4 >> 1;
        const int sub = q4 & 1;
        *reinterpret_cast<ushort4*>(sWt + il * WIL + (d & 7) * WROW
                                    + (2 * jj + (d >> 3)) * 16 + sub * 8) = h;
    }
    // ---- stage x: fp32 global -> f16 LDS, slot (b*8+il)*16B = x[b,i,0..7] ----
    {
        const int k4 = tid & 1, il = (tid >> 1) & 7, b = tid >> 4;
        const float4 w = Xv[((size_t)b * ICAP + (i0 + il)) * 2 + k4];
        ushort4 h;
        h.x = __half_as_ushort(__float2half(w.x));
        h.y = __half_as_ushort(__float2half(w.y));
        h.z = __half_as_ushort(__float2half(w.z));
        h.w = __half_as_ushort(__float2half(w.w));
        *reinterpret_cast<ushort4*>(sX + (b * 8 + il) * 16 + k4 * 8) = h;
    }
    __syncthreads();

    const int wave = tid >> 6, lane = tid & 63;
    const int j = lane & 31, dh = lane >> 5;
    float vacc = 0.f;                            // wave-0: running vsum[e]

#pragma unroll
    for (int r = 0; r < 3; ++r) {
        const bool first = (r == 0);             // constant after unroll
        float vs[4][8], sacc[4][8];
#pragma unroll
        for (int bb = 0; bb < 4; ++bb) {
            const int b = wave + 8 * bb;
            if (!first) {
                const float* vp = vsum + b * JD + j * 16 + dh * 8;
                const float4 a  = *reinterpret_cast<const float4*>(vp);
                const float4 bq = *reinterpret_cast<const float4*>(vp + 4);
                vs[bb][0]=a.x; vs[bb][1]=a.y; vs[bb][2]=a.z; vs[bb][3]=a.w;
                vs[bb][4]=bq.x; vs[bb][5]=bq.y; vs[bb][6]=bq.z; vs[bb][7]=bq.w;
            }
#pragma unroll
            for (int q = 0; q < 8; ++q) sacc[bb][q] = 0.f;
        }

#pragma unroll
        for (int il = 0; il < ICH; ++il) {
            H8 w8[8];
#pragma unroll
            for (int cc = 0; cc < 8; ++cc)
                w8[cc].i4 = *reinterpret_cast<const int4*>(
                    sWt + il * WIL + cc * WROW + (2 * j + dh) * 16);
#pragma unroll
            for (int bb = 0; bb < 4; ++bb) {
                const int b = wave + 8 * bb;
                H8 xv;
                xv.i4 = *reinterpret_cast<const int4*>(sX + (b * 8 + il) * 16);

                float u[8], tpart = 0.f;
#pragma unroll
                for (int q = 0; q < 8; ++q) {
                    float acc = FDOT2(w8[q].h[0], xv.h[0], 0.f);
                    acc = FDOT2(w8[q].h[1], xv.h[1], acc);
                    acc = FDOT2(w8[q].h[2], xv.h[2], acc);
                    acc = FDOT2(w8[q].h[3], xv.h[3], acc);
                    u[q] = acc;
                    if (!first) tpart = fmaf(acc, vs[bb][q], tpart);
                }
                float c;
                if (first) {
                    c = 0.03125f;                // softmax(0) over 32 j's
                } else {
                    const float t = tpart + __shfl_xor(tpart, 32);
                    const float e = __expf(t);
                    float se = e;
#pragma unroll
                    for (int off = 1; off <= 16; off <<= 1)
                        se += __shfl_xor(se, off);
                    c = e * FAST_RCP(se);
                }
#pragma unroll
                for (int q = 0; q < 8; ++q)
                    sacc[bb][q] = fmaf(c, u[q], sacc[bb][q]);
            }
        }

        // fp16 partial slice, disjoint per block
        __half* pout = partials + (size_t)bid * S_ELEMS;
#pragma unroll
        for (int bb = 0; bb < 4; ++bb) {
            const int b = wave + 8 * bb;
            union { int4 v; __half2 h[4]; } pk;
#pragma unroll
            for (int q = 0; q < 4; ++q)
                pk.h[q] = __floats2half2_rn(sacc[bb][2 * q], sacc[bb][2 * q + 1]);
            *reinterpret_cast<int4*>(pout + b * JD + j * 16 + dh * 8) = pk.v;
        }

        gsync(gbar, 2 * r + 1);

        // ---- reduce: block owns e in [bid*64, bid*64+64) ----
        {
            const int e = bid * 64 + lane;
            float s = 0.f;
            const __half* p = partials + (size_t)wave * 32 * S_ELEMS + e;
#pragma unroll
            for (int n = 0; n < 32; ++n)
                s += __half2float(p[(size_t)n * S_ELEMS]);
            rbuf[wave][lane] = s;
            __syncthreads();
            if (wave == 0) {
                s = 0.f;
#pragma unroll
                for (int k = 0; k < 8; ++k) s += rbuf[k][lane];
                float n2 = s * s;
#pragma unroll
                for (int off = 1; off <= 8; off <<= 1)
                    n2 += __shfl_xor(n2, off);
                const float scale = n2 * FAST_RCP(1.f + n2) * FAST_RSQ(n2 + EPSQ);
                const float v = s * scale;
                if (r == 2) {
                    out[e] = v;
                } else {
                    vacc += v;                   // vsum = sum of v's so far
                    vsum[e] = vacc;
                }
            }
        }
        if (r < 2) gsync(gbar, 2 * r + 2);
    }
}

// ===========================================================================
// Fallback path (proven 7-kernel pipeline) — used only if cooperative launch
// is rejected by the runtime/graph capture.
// ===========================================================================
__global__ __launch_bounds__(256)
void caps_prep(const float4* __restrict__ Wv, const float* __restrict__ x,
               ushort4* __restrict__ Wt, __half* __restrict__ xh) {
    const int i = blockIdx.x;
    const int t = threadIdx.x;
#pragma unroll
    for (int q = 0; q < 4; ++q) {
        const int f  = q * 256 + t;
        const int jj = f >> 5, c = f & 31;
        const float4 w = Wv[(size_t)jj * 65536 + (size_t)i * 32 + c];
        ushort4 h;
        h.x = __half_as_ushort(__float2half(w.x));
        h.y = __half_as_ushort(__float2half(w.y));
        h.z = __half_as_ushort(__float2half(w.z));
        h.w = __half_as_ushort(__float2half(w.w));
        const int dh = c >> 4, cc = (c & 15) >> 1, sub = c & 1;
        Wt[((size_t)i * 512 + cc * 64 + 2 * jj + dh) * 2 + sub] = h;
    }
    const int b = t >> 3, k = t & 7;
    const size_t xi = ((size_t)b * ICAP + i) * 8 + k;
    xh[xi] = __float2half(x[xi]);
}

template <int FIRST>
__global__ __launch_bounds__(512, 1)
void caps_pass(const int4* __restrict__ Wt, const int4* __restrict__ xh,
               const float* __restrict__ vsum, __half* __restrict__ partials) {
    const int tid  = threadIdx.x;
    const int wave = tid >> 6;
    const int lane = tid & 63;
    const int j    = lane & 31;
    const int dh   = lane >> 5;
    const int i0   = blockIdx.x * ICH;

    float vs[4][8], sacc[4][8];
#pragma unroll
    for (int bb = 0; bb < 4; ++bb) {
        const int b = wave + 8 * bb;
        if (!FIRST) {
            const float* vp = vsum + b * JD + j * 16 + dh * 8;
            const float4 a  = *reinterpret_cast<const float4*>(vp);
            const float4 bq = *reinterpret_cast<const float4*>(vp + 4);
            vs[bb][0]=a.x; vs[bb][1]=a.y; vs[bb][2]=a.z; vs[bb][3]=a.w;
            vs[bb][4]=bq.x; vs[bb][5]=bq.y; vs[bb][6]=bq.z; vs[bb][7]=bq.w;
        }
#pragma unroll
        for (int q = 0; q < 8; ++q) sacc[bb][q] = 0.f;
    }

    const int4* wp = Wt + (size_t)i0 * 512 + 2 * j + dh;

#pragma unroll
    for (int il = 0; il < ICH; ++il) {
        H8 w8[8];
#pragma unroll
        for (int cc = 0; cc < 8; ++cc)
            w8[cc].i4 = wp[(size_t)il * 512 + cc * 64];

        const int gi = i0 + il;
#pragma unroll
        for (int bb = 0; bb < 4; ++bb) {
            const int b = wave + 8 * bb;
            H8 xv;
            xv.i4 = xh[(size_t)b * ICAP + gi];

            float u[8], tpart = 0.f;
#pragma unroll
            for (int q = 0; q < 8; ++q) {
                float acc = FDOT2(w8[q].h[0], xv.h[0], 0.f);
                acc = FDOT2(w8[q].h[1], xv.h[1], acc);
                acc = FDOT2(w8[q].h[2], xv.h[2], acc);
                acc = FDOT2(w8[q].h[3], xv.h[3], acc);
                u[q] = acc;
                if (!FIRST) tpart = fmaf(acc, vs[bb][q], tpart);
            }
            float c;
            if (FIRST) {
                c = 0.03125f;
            } else {
                const float t = tpart + __shfl_xor(tpart, 32);
                const float e = __expf(t);
                float se = e;
#pragma unroll
                for (int off = 1; off <= 16; off <<= 1)
                    se += __shfl_xor(se, off);
                c = e * FAST_RCP(se);
            }
#pragma unroll
            for (int q = 0; q < 8; ++q)
                sacc[bb][q] = fmaf(c, u[q], sacc[bb][q]);
        }
    }

    __half* pout = partials + (size_t)blockIdx.x * S_ELEMS;
#pragma unroll
    for (int bb = 0; bb < 4; ++bb) {
        const int b = wave + 8 * bb;
        union { int4 v; __half2 h[4]; } pk;
#pragma unroll
        for (int q = 0; q < 4; ++q)
            pk.h[q] = __floats2half2_rn(sacc[bb][2 * q], sacc[bb][2 * q + 1]);
        *reinterpret_cast<int4*>(pout + b * JD + j * 16 + dh * 8) = pk.v;
    }
}

__global__ __launch_bounds__(1024)
void caps_reduce(const __half* __restrict__ partials, float* __restrict__ vsum,
                 float* __restrict__ out, int first) {
    __shared__ float buf[16][80];
    const int tid = threadIdx.x;
    const int eL  = tid & 63;
    const int sg  = tid >> 6;
    const int e   = blockIdx.x * 64 + eL;

    float s = 0.f;
    const __half* p = partials + (size_t)sg * S_ELEMS + e;
#pragma unroll
    for (int n = 0; n < 16; ++n)
        s += __half2float(p[(size_t)(n * 16) * S_ELEMS]);
    buf[sg][eL] = s;
    __syncthreads();

    if (sg == 0) {
        s = 0.f;
#pragma unroll
        for (int k = 0; k < 16; ++k) s += buf[k][eL];
        float n2 = s * s;
#pragma unroll
        for (int off = 1; off <= 8; off <<= 1)
            n2 += __shfl_xor(n2, off);
        const float scale = n2 * FAST_RCP(1.f + n2) * FAST_RSQ(n2 + EPSQ);
        const float v = s * scale;
        const float old = first ? 0.f : vsum[e];
        vsum[e] = old + v;
        if (out) out[e] = v;
    }
}

extern "C" void kernel_launch(void* const* d_in, const int* in_sizes, int n_in,
                              void* d_out, int out_size, void* d_ws, size_t ws_size,
                              hipStream_t stream) {
    const float* x = (const float*)d_in[0];   // [32,2048,8]
    const float* W = (const float*)d_in[1];   // [32,2048,16,8]
    float* out = (float*)d_out;               // [32,32,16]

    // ws: vsum 64KB | partials fp16 8.39MB | gbar 256B | fallback Wt 16.78MB | xh
    float*    vsum     = (float*)d_ws;
    __half*   partials = (__half*)((char*)d_ws + 65536);
    unsigned* gbar     = (unsigned*)((char*)partials + (size_t)NBP * S_ELEMS * 2);
    ushort4*  Wt       = (ushort4*)((char*)gbar + 256);
    __half*   xh       = (__half*)((char*)Wt + (size_t)ICAP * 512 * 16);

    // zero barrier state (counter @0, release flag @128)
    hipMemsetAsync(gbar, 0, 256, stream);

    const float4* W4 = (const float4*)W;
    const float4* x4 = (const float4*)x;
    void* args[] = {(void*)&W4, (void*)&x4, (void*)&vsum, (void*)&partials,
                    (void*)&out, (void*)&gbar};

    hipError_t cerr = hipLaunchCooperativeKernel(
        reinterpret_cast<const void*>(&caps_fused),
        dim3(NBP), dim3(512), args, 0, stream);

    if (cerr != hipSuccess) {
        (void)hipGetLastError();  // clear sticky error, use proven path
        caps_prep<<<ICAP, 256, 0, stream>>>((const float4*)W, x, Wt, xh);
        caps_pass<1><<<NBP, 512, 0, stream>>>((const int4*)Wt, (const int4*)xh,
                                              vsum, partials);
        caps_reduce<<<S_ELEMS / 64, 1024, 0, stream>>>(partials, vsum, nullptr, 1);
        caps_pass<0><<<NBP, 512, 0, stream>>>((const int4*)Wt, (const int4*)xh,
                                              vsum, partials);
        caps_reduce<<<S_ELEMS / 64, 1024, 0, stream>>>(partials, vsum, nullptr, 0);
        caps_pass<0><<<NBP, 512, 0, stream>>>((const int4*)Wt, (const int4*)xh,
                                              vsum, partials);
        caps_reduce<<<S_ELEMS / 64, 1024, 0, stream>>>(partials, vsum, out, 0);
    }
}